// Round 1
// baseline (3985.218 us; speedup 1.0000x reference)
//
#include <hip/hip_runtime.h>
#include <stdint.h>
#include <math.h>

#define N_NODES 1000
#define DIM 256
#define N_EDGES 16000
#define NS 8            // gumbel samples
#define P 2000          // padded sinkhorn size
#define IC 16           // col-pass row chunks
#define ROWS_PER (P / IC)

// ---------------- Threefry-2x32 (exact JAX) ----------------
__host__ __device__ inline void tf2x32(uint32_t k0, uint32_t k1,
                                       uint32_t x0, uint32_t x1,
                                       uint32_t* o0, uint32_t* o1) {
  const uint32_t ks2 = k0 ^ k1 ^ 0x1BD11BDAu;
  uint32_t a = x0 + k0, b = x1 + k1;
#define RL(v, d) (((v) << (d)) | ((v) >> (32 - (d))))
#define RND(r) { a += b; b = RL(b, r); b ^= a; }
  RND(13) RND(15) RND(26) RND(6)
  a += k1;  b += ks2 + 1u;
  RND(17) RND(29) RND(16) RND(24)
  a += ks2; b += k0 + 2u;
  RND(13) RND(15) RND(26) RND(6)
  a += k0;  b += k1 + 3u;
  RND(17) RND(29) RND(16) RND(24)
  a += k1;  b += ks2 + 4u;
  RND(13) RND(15) RND(26) RND(6)
  a += ks2; b += k0 + 5u;
#undef RND
#undef RL
  *o0 = a; *o1 = b;
}

// partitionable 32-bit bits: xor-fold of cipher(hi=0, lo=idx)
__device__ inline float gumbel_from_idx(uint32_t k0, uint32_t k1, uint32_t idx) {
  uint32_t b0, b1;
  tf2x32(k0, k1, 0u, idx, &b0, &b1);
  uint32_t bits = b0 ^ b1;
  float u = __uint_as_float((bits >> 9) | 0x3f800000u) - 1.0f;
  return -logf(-logf(u + 1e-20f) + 1e-20f);
}

// ---------------- block reductions (blockDim==256) ----------------
__device__ inline float blockSum256(float v) {
  __shared__ float sm[4];
  #pragma unroll
  for (int off = 32; off; off >>= 1) v += __shfl_down(v, off, 64);
  if ((threadIdx.x & 63) == 0) sm[threadIdx.x >> 6] = v;
  __syncthreads();
  float r = (sm[0] + sm[1]) + (sm[2] + sm[3]);
  __syncthreads();
  return r;
}
__device__ inline float blockMax256(float v) {
  __shared__ float sm[4];
  #pragma unroll
  for (int off = 32; off; off >>= 1) v = fmaxf(v, __shfl_down(v, off, 64));
  if ((threadIdx.x & 63) == 0) sm[threadIdx.x >> 6] = v;
  __syncthreads();
  float r = fmaxf(fmaxf(sm[0], sm[1]), fmaxf(sm[2], sm[3]));
  __syncthreads();
  return r;
}

// ---------------- small kernels ----------------
__global__ void k_ones(float* imp_s, float* imp_t) {
  int t = blockIdx.x * 256 + threadIdx.x;
  if (t < N_NODES) { imp_s[t] = 1.0f; imp_t[t] = 1.0f; }
}

__global__ void k_rowsum(const float* __restrict__ thp, float* __restrict__ imp) {
  int i = blockIdx.x;
  float a = 0.f;
  for (int j = threadIdx.x; j < N_NODES; j += 256) a += thp[(size_t)i * N_NODES + j];
  float s = blockSum256(a);
  if (threadIdx.x == 0) imp[i] = s;
}

__global__ void k_colsum(const float* __restrict__ thp, float* __restrict__ imp) {
  int j = blockIdx.x * 256 + threadIdx.x;
  if (j >= N_NODES) return;
  float a = 0.f;
  for (int i = 0; i < N_NODES; ++i) a += thp[(size_t)i * N_NODES + j];
  imp[j] = a;
}

__global__ void k_scale(const float* __restrict__ x, const float* __restrict__ imp,
                        float* __restrict__ h) {
  int i = blockIdx.x, d = threadIdx.x;
  h[i * DIM + d] = x[i * DIM + d] * imp[i];
}

__global__ void k_agg(const float* __restrict__ h, const int* __restrict__ e,
                      float* __restrict__ agg) {
  int eid = blockIdx.x, d = threadIdx.x;
  int src = e[eid], dst = e[N_EDGES + eid];
  atomicAdd(&agg[dst * DIM + d], h[src * DIM + d]);
}

// out = act((h+agg) @ Wm + bias); M=1000,K=N=256. tile 16x64
__global__ void __launch_bounds__(256) k_lin(const float* __restrict__ h,
    const float* __restrict__ agg, const float* __restrict__ Wm,
    const float* __restrict__ bias, float* __restrict__ out, int relu) {
  __shared__ float As[16][64];
  __shared__ float Ws[64][64];
  int tx = threadIdx.x & 63;
  int ty = threadIdx.x >> 6;
  int row0 = blockIdx.x * 16;
  int col0 = blockIdx.y * 64;
  float acc[4] = {0.f, 0.f, 0.f, 0.f};
  for (int kc = 0; kc < DIM; kc += 64) {
    for (int t = threadIdx.x; t < 16 * 64; t += 256) {
      int r = t >> 6, c = t & 63;
      int gr = row0 + r;
      As[r][c] = (gr < N_NODES) ? (h[gr * DIM + kc + c] + agg[gr * DIM + kc + c]) : 0.f;
    }
    for (int t = threadIdx.x; t < 64 * 64; t += 256) {
      int r = t >> 6, c = t & 63;
      Ws[r][c] = Wm[(kc + r) * DIM + col0 + c];
    }
    __syncthreads();
    #pragma unroll 8
    for (int kk = 0; kk < 64; ++kk) {
      float w = Ws[kk][tx];
      acc[0] += As[ty][kk] * w;
      acc[1] += As[ty + 4][kk] * w;
      acc[2] += As[ty + 8][kk] * w;
      acc[3] += As[ty + 12][kk] * w;
    }
    __syncthreads();
  }
  int col = col0 + tx;
  float bv = bias[col];
  #pragma unroll
  for (int r = 0; r < 4; ++r) {
    int gr = row0 + ty + r * 4;
    if (gr < N_NODES) {
      float vv = acc[r] + bv;
      if (relu) vv = fmaxf(vv, 0.f);
      out[gr * DIM + col] = vv;
    }
  }
}

__global__ void k_norm(const float* __restrict__ h, float* __restrict__ out) {
  int i = blockIdx.x;
  float x = h[i * DIM + threadIdx.x];
  float ss = blockSum256(x * x);
  float nrm = sqrtf(ss);
  out[i * DIM + threadIdx.x] = x / nrm;
}

// C[i][j] = 50 * dot(A[i,:], B[j,:]) ; A,B 1000x256, C 1000x1000
__global__ void __launch_bounds__(256) k_gemm50(const float* __restrict__ A,
    const float* __restrict__ B, float* __restrict__ C) {
  __shared__ float As[64][33];
  __shared__ float Bs[64][33];
  int tr = threadIdx.x >> 4;
  int tc = threadIdx.x & 15;
  int i0 = blockIdx.x * 64, j0 = blockIdx.y * 64;
  float acc[4][4] = {};
  for (int kc = 0; kc < DIM; kc += 32) {
    for (int t = threadIdx.x; t < 64 * 32; t += 256) {
      int r = t >> 5, c = t & 31;
      int gi = i0 + r; As[r][c] = (gi < N_NODES) ? A[gi * DIM + kc + c] : 0.f;
      int gj = j0 + r; Bs[r][c] = (gj < N_NODES) ? B[gj * DIM + kc + c] : 0.f;
    }
    __syncthreads();
    for (int kk = 0; kk < 32; ++kk) {
      float a[4], b[4];
      #pragma unroll
      for (int q = 0; q < 4; ++q) a[q] = As[tr * 4 + q][kk];
      #pragma unroll
      for (int q = 0; q < 4; ++q) b[q] = Bs[tc * 4 + q][kk];
      #pragma unroll
      for (int r = 0; r < 4; ++r)
        #pragma unroll
        for (int c = 0; c < 4; ++c) acc[r][c] += a[r] * b[c];
    }
    __syncthreads();
  }
  for (int r = 0; r < 4; ++r) {
    int gi = i0 + tr * 4 + r;
    if (gi >= N_NODES) continue;
    for (int c = 0; c < 4; ++c) {
      int gj = j0 + tc * 4 + c;
      if (gj < N_NODES) C[(size_t)gi * N_NODES + gj] = 50.0f * acc[r][c];
    }
  }
}

// base = (pad(la) + gumbel)/tau ; fused row-normalize #1 -> u
__global__ void __launch_bounds__(256) k_build(const float* __restrict__ la,
    float* __restrict__ base, float* __restrict__ u, uint32_t k0, uint32_t k1) {
  int i = blockIdx.x;   // 0..1999
  int s = blockIdx.y;   // 0..7
  float* brow = base + ((size_t)s * P + i) * P;
  const int j0 = threadIdx.x * 8;
  float bv[8];
  float lmax = -INFINITY;
  if (j0 < P) {
    uint32_t idxbase = (uint32_t)((s * P + i) * P + j0);
    #pragma unroll
    for (int q = 0; q < 8; ++q) {
      int j = j0 + q;
      float g = gumbel_from_idx(k0, k1, idxbase + (uint32_t)q);
      float lav = (i < N_NODES && j < N_NODES) ? la[(size_t)i * N_NODES + j] : 0.0f;
      bv[q] = (lav + g) / 0.1f;
      lmax = fmaxf(lmax, bv[q]);
    }
    float4* p = (float4*)(brow + j0);
    p[0] = make_float4(bv[0], bv[1], bv[2], bv[3]);
    p[1] = make_float4(bv[4], bv[5], bv[6], bv[7]);
  }
  float M = blockMax256(lmax);
  float ls = 0.f;
  if (j0 < P) {
    #pragma unroll
    for (int q = 0; q < 8; ++q) ls += expf(bv[q] - M);
  }
  float S = blockSum256(ls);
  if (threadIdx.x == 0) u[s * P + i] = M + logf(S);
}

// col-pass partial: online LSE over a row chunk, per column
__global__ void k_colpartial(const float* __restrict__ base, const float* __restrict__ u,
                             float* __restrict__ pm, float* __restrict__ ps) {
  int j = blockIdx.x * 256 + threadIdx.x;
  int ic = blockIdx.y;
  int s = blockIdx.z;
  float m = -INFINITY, l = 0.f;
  if (j < P) {
    const float* b = base + ((size_t)s * P + ic * ROWS_PER) * P + j;
    const float* uu = u + s * P + ic * ROWS_PER;
    #pragma unroll 4
    for (int r = 0; r < ROWS_PER; ++r) {
      float x = b[(size_t)r * P] - uu[r];
      if (x > m) { l = l * expf(m - x) + 1.0f; m = x; }
      else l += expf(x - m);
    }
  }
  int o = (s * IC + ic) * 2048 + blockIdx.x * 256 + threadIdx.x;
  pm[o] = m; ps[o] = l;
}

__global__ void k_colcombine(const float* __restrict__ pm, const float* __restrict__ ps,
                             float* __restrict__ v) {
  int j = blockIdx.x * 256 + threadIdx.x;
  int s = blockIdx.y;
  if (j >= P) return;
  float M = -INFINITY;
  for (int c = 0; c < IC; ++c) M = fmaxf(M, pm[(s * IC + c) * 2048 + j]);
  float S = 0.f;
  for (int c = 0; c < IC; ++c) {
    int o = (s * IC + c) * 2048 + j;
    S += ps[o] * expf(pm[o] - M);
  }
  v[s * P + j] = M + logf(S);
}

// row pass: u_i = LSE_j(base - v_j)
__global__ void __launch_bounds__(256) k_row(const float* __restrict__ base,
    const float* __restrict__ v, float* __restrict__ u) {
  int i = blockIdx.x, s = blockIdx.y;
  const float* brow = base + ((size_t)s * P + i) * P;
  const float* vv = v + s * P;
  int j0 = threadIdx.x * 8;
  float x[8];
  float lmax = -INFINITY;
  if (j0 < P) {
    float4 b0 = *(const float4*)(brow + j0);
    float4 b1 = *(const float4*)(brow + j0 + 4);
    float4 v0 = *(const float4*)(vv + j0);
    float4 v1 = *(const float4*)(vv + j0 + 4);
    x[0] = b0.x - v0.x; x[1] = b0.y - v0.y; x[2] = b0.z - v0.z; x[3] = b0.w - v0.w;
    x[4] = b1.x - v1.x; x[5] = b1.y - v1.y; x[6] = b1.z - v1.z; x[7] = b1.w - v1.w;
    #pragma unroll
    for (int q = 0; q < 8; ++q) lmax = fmaxf(lmax, x[q]);
  }
  float M = blockMax256(lmax);
  float ls = 0.f;
  if (j0 < P) {
    #pragma unroll
    for (int q = 0; q < 8; ++q) ls += expf(x[q] - M);
  }
  float S = blockSum256(ls);
  if (threadIdx.x == 0) u[s * P + i] = M + logf(S);
}

// theta[s,i,j] = exp(base - u - v), only top-left 1000x1000 block
__global__ void k_theta(const float* __restrict__ base, const float* __restrict__ u,
                        const float* __restrict__ v, float* __restrict__ th) {
  int i = blockIdx.x, s = blockIdx.y;
  int j0 = threadIdx.x * 4;
  if (j0 >= N_NODES) return;
  float ui = u[s * P + i];
  const float* brow = base + ((size_t)s * P + i) * P;
  float4 b = *(const float4*)(brow + j0);
  float4 vv = *(const float4*)(v + s * P + j0);
  float4 t;
  t.x = expf(b.x - ui - vv.x);
  t.y = expf(b.y - ui - vv.y);
  t.z = expf(b.z - ui - vv.z);
  t.w = expf(b.w - ui - vv.w);
  *(float4*)(th + ((size_t)s * N_NODES + i) * N_NODES + j0) = t;
}

__global__ void k_thmean(const float* __restrict__ th, float* __restrict__ thp) {
  int idx = blockIdx.x * 256 + threadIdx.x;
  if (idx < N_NODES * N_NODES) {
    float a = 0.f;
    for (int s = 0; s < NS; ++s) a += th[(size_t)s * N_NODES * N_NODES + idx];
    thp[idx] = a * 0.125f;
  }
}

// W[s,i,c] = sum_{k: e2_0[k]=c} theta[s,i,e2_1[k]]
__global__ void __launch_bounds__(256) k_wbuild(const float* __restrict__ th,
    const int* __restrict__ et, float* __restrict__ Wb) {
  __shared__ float trow[N_NODES];
  __shared__ float wrow[N_NODES];
  int i = blockIdx.x, s = blockIdx.y;
  const float* tr = th + ((size_t)s * N_NODES + i) * N_NODES;
  for (int j = threadIdx.x; j < N_NODES; j += 256) { trow[j] = tr[j]; wrow[j] = 0.f; }
  __syncthreads();
  for (int k = threadIdx.x; k < N_EDGES; k += 256) {
    int c = et[k];
    int sc = et[N_EDGES + k];
    atomicAdd(&wrow[c], trow[sc]);
  }
  __syncthreads();
  float* wout = Wb + ((size_t)s * N_NODES + i) * N_NODES;
  for (int j = threadIdx.x; j < N_NODES; j += 256) wout[j] = wrow[j];
}

// matched[s] += sum over e1 edges of dot(W[s,e1_0], theta[s,e1_1])
__global__ void __launch_bounds__(256) k_matched(const float* __restrict__ Wb,
    const float* __restrict__ th, const int* __restrict__ es, float* __restrict__ matched) {
  int chunk = blockIdx.x;   // 0..249 (64 edges each)
  int s = blockIdx.y;
  int wave = threadIdx.x >> 6, lane = threadIdx.x & 63;
  float acc = 0.f;
  for (int e = 0; e < 16; ++e) {
    int k = chunk * 64 + wave * 16 + e;
    int a = es[k], b = es[N_EDGES + k];
    const float4* wr = (const float4*)(Wb + ((size_t)s * N_NODES + a) * N_NODES);
    const float4* tr = (const float4*)(th + ((size_t)s * N_NODES + b) * N_NODES);
    #pragma unroll
    for (int q = 0; q < 4; ++q) {
      int f = q * 64 + lane;
      if (f < 250) {
        float4 w4 = wr[f], t4 = tr[f];
        acc += w4.x * t4.x + w4.y * t4.y + w4.z * t4.z + w4.w * t4.w;
      }
    }
  }
  #pragma unroll
  for (int off = 32; off; off >>= 1) acc += __shfl_down(acc, off, 64);
  if (lane == 0) atomicAdd(matched + s, acc);
}

__global__ void k_fin0(const float* __restrict__ matched, float* __restrict__ scal) {
  if (threadIdx.x == 0) {
    float accm = 0.f;
    for (int s = 0; s < NS; ++s) {
      float m = matched[s];
      float rv = m + (-1.0f) * ((16000.0f - m) + (16000.0f - m));
      accm += rv;
    }
    scal[0] = (accm / 8.0f) / 16000.0f;   // r0
  }
}

__global__ void k_fin1(const float* __restrict__ matched, float* __restrict__ scal,
                       float* __restrict__ out) {
  if (threadIdx.x == 0) {
    float accm = 0.f;
    for (int s = 0; s < NS; ++s) {
      float m = matched[s];
      float rv = m + (-1.0f) * ((16000.0f - m) + (16000.0f - m));
      accm += rv;
    }
    float r1 = (accm / 8.0f) / 16000.0f;
    float r0 = scal[0];
    int improved = (r1 > r0) ? 1 : 0;
    scal[1] = r1;
    scal[2] = (float)improved;
    float loss = -r0 - (improved ? r1 : 0.f);
    float cnt = improved ? 2.0f : 1.0f;
    out[(size_t)P * P] = loss / cnt;
  }
}

// write out = pad(la) (2000x2000). cond: only if scal[2]!=0
__global__ void k_out(const float* __restrict__ la, float* __restrict__ out,
                      const float* __restrict__ scal, int cond) {
  if (cond && scal[2] == 0.0f) return;
  int q = blockIdx.x * 256 + threadIdx.x;   // float4 index
  if (q >= P * P / 4) return;
  int row = q / (P / 4);
  int jc = (q % (P / 4)) * 4;
  float4 vv = make_float4(0.f, 0.f, 0.f, 0.f);
  if (row < N_NODES && jc < N_NODES)
    vv = *(const float4*)(la + (size_t)row * N_NODES + jc);
  *(float4*)(out + (size_t)row * P + jc) = vv;
}

// ---------------- launch ----------------
extern "C" void kernel_launch(void* const* d_in, const int* in_sizes, int n_in,
                              void* d_out, int out_size, void* d_ws, size_t ws_size,
                              hipStream_t stream) {
  (void)in_sizes; (void)n_in; (void)out_size; (void)ws_size;
  const float* x_s = (const float*)d_in[0];
  const int*   e_s = (const int*)d_in[1];
  const float* x_t = (const float*)d_in[2];
  const int*   e_t = (const int*)d_in[3];
  const float* W1  = (const float*)d_in[4];
  const float* b1  = (const float*)d_in[5];
  const float* W2  = (const float*)d_in[6];
  const float* b2  = (const float*)d_in[7];
  float* out = (float*)d_out;

  // workspace layout (floats)
  float* ws    = (float*)d_ws;
  float* base  = ws;                       // 32,000,000
  float* theta = base + 32000000;          //  8,000,000
  float* Wb    = theta + 8000000;          //  8,000,000
  float* laA   = Wb + 8000000;             //  1,000,000
  float* laB   = laA + 1000000;            //  1,000,000
  float* thp   = laB + 1000000;            //  1,000,000
  float* h0    = thp + 1000000;            //    256,000
  float* agg   = h0 + 256000;
  float* h1    = agg + 256000;
  float* h2    = h1 + 256000;
  float* hsn   = h2 + 256000;
  float* htn   = hsn + 256000;
  float* uarr  = htn + 256000;             //     16,000
  float* varr  = uarr + 16000;             //     16,000
  float* pm    = varr + 16000;             //    262,144
  float* psum  = pm + 262144;              //    262,144
  float* imp_s = psum + 262144;            //      1,024
  float* imp_t = imp_s + 1024;             //      1,024
  float* matched = imp_t + 1024;           //         16
  float* scal  = matched + 16;             //         16

  // host-side JAX key schedule: key(42)=[0,42]; foldlike split (partitionable)
  uint32_t k0 = 0u, k1 = 42u;
  uint32_t sub[2][2];
  for (int it = 0; it < 2; ++it) {
    uint32_t nk0, nk1, s0, s1;
    tf2x32(k0, k1, 0u, 0u, &nk0, &nk1);   // next carry key = cipher(0,0)
    tf2x32(k0, k1, 0u, 1u, &s0, &s1);     // subkey        = cipher(0,1)
    sub[it][0] = s0; sub[it][1] = s1;
    k0 = nk0; k1 = nk1;
  }

  for (int it = 0; it < 2; ++it) {
    // importance
    if (it == 0) {
      k_ones<<<4, 256, 0, stream>>>(imp_s, imp_t);
    } else {
      k_rowsum<<<N_NODES, 256, 0, stream>>>(thp, imp_s);
      k_colsum<<<4, 256, 0, stream>>>(thp, imp_t);
    }
    // GNN per graph
    for (int g = 0; g < 2; ++g) {
      const float* x   = g ? x_t : x_s;
      const int*   e   = g ? e_t : e_s;
      const float* imp = g ? imp_t : imp_s;
      float* hn        = g ? htn : hsn;
      k_scale<<<N_NODES, 256, 0, stream>>>(x, imp, h0);
      hipMemsetAsync(agg, 0, (size_t)N_NODES * DIM * 4, stream);
      k_agg<<<N_EDGES, 256, 0, stream>>>(h0, e, agg);
      k_lin<<<dim3(63, 4), 256, 0, stream>>>(h0, agg, W1, b1, h1, 1);
      hipMemsetAsync(agg, 0, (size_t)N_NODES * DIM * 4, stream);
      k_agg<<<N_EDGES, 256, 0, stream>>>(h1, e, agg);
      k_lin<<<dim3(63, 4), 256, 0, stream>>>(h1, agg, W2, b2, h2, 0);
      k_norm<<<N_NODES, 256, 0, stream>>>(h2, hn);
    }
    // similarity
    float* la = it ? laB : laA;
    k_gemm50<<<dim3(16, 16), 256, 0, stream>>>(hsn, htn, la);
    // gumbel + sinkhorn (10 iterations; row pass 0 fused in build)
    k_build<<<dim3(P, NS), 256, 0, stream>>>(la, base, uarr, sub[it][0], sub[it][1]);
    for (int k = 0; k < 10; ++k) {
      k_colpartial<<<dim3(8, IC, NS), 256, 0, stream>>>(base, uarr, pm, psum);
      k_colcombine<<<dim3(8, NS), 256, 0, stream>>>(pm, psum, varr);
      if (k < 9) k_row<<<dim3(P, NS), 256, 0, stream>>>(base, varr, uarr);
    }
    // theta + reward
    k_theta<<<dim3(N_NODES, NS), 256, 0, stream>>>(base, uarr, varr, theta);
    if (it == 0) k_thmean<<<3907, 256, 0, stream>>>(theta, thp);
    k_wbuild<<<dim3(N_NODES, NS), 256, 0, stream>>>(theta, e_t, Wb);
    hipMemsetAsync(matched, 0, NS * 4, stream);
    k_matched<<<dim3(250, NS), 256, 0, stream>>>(Wb, theta, e_s, matched);
    if (it == 0) {
      k_fin0<<<1, 64, 0, stream>>>(matched, scal);
      k_out<<<3907, 256, 0, stream>>>(laA, out, scal, 0);
    } else {
      k_fin1<<<1, 64, 0, stream>>>(matched, scal, out);
      k_out<<<3907, 256, 0, stream>>>(laB, out, scal, 1);
    }
  }
}

// Round 2
// 2301.685 us; speedup vs baseline: 1.7314x; 1.7314x over previous
//
#include <hip/hip_runtime.h>
#include <stdint.h>
#include <math.h>

#define N_NODES 1000
#define DIM 256
#define N_EDGES 16000
#define NS 8            // gumbel samples
#define P 2000          // padded sinkhorn size
#define IC 16           // col-pass row chunks
#define ROWS_PER (P / IC)

// ---------------- Threefry-2x32 (exact JAX) ----------------
__host__ __device__ inline void tf2x32(uint32_t k0, uint32_t k1,
                                       uint32_t x0, uint32_t x1,
                                       uint32_t* o0, uint32_t* o1) {
  const uint32_t ks2 = k0 ^ k1 ^ 0x1BD11BDAu;
  uint32_t a = x0 + k0, b = x1 + k1;
#define RL(v, d) (((v) << (d)) | ((v) >> (32 - (d))))
#define RND(r) { a += b; b = RL(b, r); b ^= a; }
  RND(13) RND(15) RND(26) RND(6)
  a += k1;  b += ks2 + 1u;
  RND(17) RND(29) RND(16) RND(24)
  a += ks2; b += k0 + 2u;
  RND(13) RND(15) RND(26) RND(6)
  a += k0;  b += k1 + 3u;
  RND(17) RND(29) RND(16) RND(24)
  a += k1;  b += ks2 + 4u;
  RND(13) RND(15) RND(26) RND(6)
  a += ks2; b += k0 + 5u;
#undef RND
#undef RL
  *o0 = a; *o1 = b;
}

// partitionable 32-bit bits: xor-fold of cipher(hi=0, lo=idx)
__device__ inline float gumbel_from_idx(uint32_t k0, uint32_t k1, uint32_t idx) {
  uint32_t b0, b1;
  tf2x32(k0, k1, 0u, idx, &b0, &b1);
  uint32_t bits = b0 ^ b1;
  float u = __uint_as_float((bits >> 9) | 0x3f800000u) - 1.0f;
  return -logf(-logf(u + 1e-20f) + 1e-20f);
}

// ---------------- block reductions (blockDim==256) ----------------
__device__ inline float blockSum256(float v) {
  __shared__ float sm[4];
  #pragma unroll
  for (int off = 32; off; off >>= 1) v += __shfl_down(v, off, 64);
  if ((threadIdx.x & 63) == 0) sm[threadIdx.x >> 6] = v;
  __syncthreads();
  float r = (sm[0] + sm[1]) + (sm[2] + sm[3]);
  __syncthreads();
  return r;
}
__device__ inline float blockMax256(float v) {
  __shared__ float sm[4];
  #pragma unroll
  for (int off = 32; off; off >>= 1) v = fmaxf(v, __shfl_down(v, off, 64));
  if ((threadIdx.x & 63) == 0) sm[threadIdx.x >> 6] = v;
  __syncthreads();
  float r = fmaxf(fmaxf(sm[0], sm[1]), fmaxf(sm[2], sm[3]));
  __syncthreads();
  return r;
}

// ---------------- CSR build (edge lists are static; built once per launch) --
__global__ void k_hist(const int* __restrict__ key, int* __restrict__ cnt) {
  int k = blockIdx.x * 256 + threadIdx.x;
  if (k < N_EDGES) atomicAdd(&cnt[key[k]], 1);
}
__global__ void k_scan(const int* __restrict__ cnt, int* __restrict__ start) {
  __shared__ int sm[1024];
  int t = threadIdx.x;
  sm[t] = (t < N_NODES) ? cnt[t] : 0;
  __syncthreads();
  for (int off = 1; off < 1024; off <<= 1) {
    int v = (t >= off) ? sm[t - off] : 0;
    __syncthreads();
    sm[t] += v;
    __syncthreads();
  }
  if (t < N_NODES) start[t + 1] = sm[t];
  if (t == 0) start[0] = 0;
}
__global__ void k_scatter(const int* __restrict__ key, const int* __restrict__ start,
                          int* __restrict__ cursor, int* __restrict__ ids) {
  int k = blockIdx.x * 256 + threadIdx.x;
  if (k < N_EDGES) {
    int c = key[k];
    int slot = start[c] + atomicAdd(&cursor[c], 1);
    ids[slot] = k;
  }
}
__global__ void k_partfill(const int* __restrict__ ids, const int* __restrict__ pv,
                           int* __restrict__ part) {
  int s = blockIdx.x * 256 + threadIdx.x;
  if (s < N_EDGES) part[s] = pv[ids[s]];
}

// ---------------- small kernels ----------------
__global__ void k_ones(float* imp_s, float* imp_t) {
  int t = blockIdx.x * 256 + threadIdx.x;
  if (t < N_NODES) { imp_s[t] = 1.0f; imp_t[t] = 1.0f; }
}

__global__ void k_rowsum(const float* __restrict__ thp, float* __restrict__ imp) {
  int i = blockIdx.x;
  float a = 0.f;
  for (int j = threadIdx.x; j < N_NODES; j += 256) a += thp[(size_t)i * N_NODES + j];
  float s = blockSum256(a);
  if (threadIdx.x == 0) imp[i] = s;
}

__global__ void k_colsum(const float* __restrict__ thp, float* __restrict__ imp) {
  int j = blockIdx.x * 256 + threadIdx.x;
  if (j >= N_NODES) return;
  float a = 0.f;
  for (int i = 0; i < N_NODES; ++i) a += thp[(size_t)i * N_NODES + j];
  imp[j] = a;
}

__global__ void k_scale(const float* __restrict__ x, const float* __restrict__ imp,
                        float* __restrict__ h) {
  int i = blockIdx.x, d = threadIdx.x;
  h[i * DIM + d] = x[i * DIM + d] * imp[i];
}

// gather form of segment_sum: agg[i,d] = sum over CSR[dst=i] of h[src,d]
__global__ void k_agg_csr(const float* __restrict__ h, const int* __restrict__ start,
                          const int* __restrict__ part, float* __restrict__ agg) {
  int i = blockIdx.x, d = threadIdx.x;
  int e0 = start[i], e1 = start[i + 1];
  float a = 0.f;
  for (int q = e0; q < e1; ++q) a += h[(size_t)part[q] * DIM + d];
  agg[i * DIM + d] = a;
}

// out = act((h+agg) @ Wm + bias); M=1000,K=N=256. tile 16x64
__global__ void __launch_bounds__(256) k_lin(const float* __restrict__ h,
    const float* __restrict__ agg, const float* __restrict__ Wm,
    const float* __restrict__ bias, float* __restrict__ out, int relu) {
  __shared__ float As[16][64];
  __shared__ float Ws[64][64];
  int tx = threadIdx.x & 63;
  int ty = threadIdx.x >> 6;
  int row0 = blockIdx.x * 16;
  int col0 = blockIdx.y * 64;
  float acc[4] = {0.f, 0.f, 0.f, 0.f};
  for (int kc = 0; kc < DIM; kc += 64) {
    for (int t = threadIdx.x; t < 16 * 64; t += 256) {
      int r = t >> 6, c = t & 63;
      int gr = row0 + r;
      As[r][c] = (gr < N_NODES) ? (h[gr * DIM + kc + c] + agg[gr * DIM + kc + c]) : 0.f;
    }
    for (int t = threadIdx.x; t < 64 * 64; t += 256) {
      int r = t >> 6, c = t & 63;
      Ws[r][c] = Wm[(kc + r) * DIM + col0 + c];
    }
    __syncthreads();
    #pragma unroll 8
    for (int kk = 0; kk < 64; ++kk) {
      float w = Ws[kk][tx];
      acc[0] += As[ty][kk] * w;
      acc[1] += As[ty + 4][kk] * w;
      acc[2] += As[ty + 8][kk] * w;
      acc[3] += As[ty + 12][kk] * w;
    }
    __syncthreads();
  }
  int col = col0 + tx;
  float bv = bias[col];
  #pragma unroll
  for (int r = 0; r < 4; ++r) {
    int gr = row0 + ty + r * 4;
    if (gr < N_NODES) {
      float vv = acc[r] + bv;
      if (relu) vv = fmaxf(vv, 0.f);
      out[gr * DIM + col] = vv;
    }
  }
}

__global__ void k_norm(const float* __restrict__ h, float* __restrict__ out) {
  int i = blockIdx.x;
  float x = h[i * DIM + threadIdx.x];
  float ss = blockSum256(x * x);
  float nrm = sqrtf(ss);
  out[i * DIM + threadIdx.x] = x / nrm;
}

// C[i][j] = 50 * dot(A[i,:], B[j,:]) ; A,B 1000x256, C 1000x1000
__global__ void __launch_bounds__(256) k_gemm50(const float* __restrict__ A,
    const float* __restrict__ B, float* __restrict__ C) {
  __shared__ float As[64][33];
  __shared__ float Bs[64][33];
  int tr = threadIdx.x >> 4;
  int tc = threadIdx.x & 15;
  int i0 = blockIdx.x * 64, j0 = blockIdx.y * 64;
  float acc[4][4] = {};
  for (int kc = 0; kc < DIM; kc += 32) {
    for (int t = threadIdx.x; t < 64 * 32; t += 256) {
      int r = t >> 5, c = t & 31;
      int gi = i0 + r; As[r][c] = (gi < N_NODES) ? A[gi * DIM + kc + c] : 0.f;
      int gj = j0 + r; Bs[r][c] = (gj < N_NODES) ? B[gj * DIM + kc + c] : 0.f;
    }
    __syncthreads();
    for (int kk = 0; kk < 32; ++kk) {
      float a[4], b[4];
      #pragma unroll
      for (int q = 0; q < 4; ++q) a[q] = As[tr * 4 + q][kk];
      #pragma unroll
      for (int q = 0; q < 4; ++q) b[q] = Bs[tc * 4 + q][kk];
      #pragma unroll
      for (int r = 0; r < 4; ++r)
        #pragma unroll
        for (int c = 0; c < 4; ++c) acc[r][c] += a[r] * b[c];
    }
    __syncthreads();
  }
  for (int r = 0; r < 4; ++r) {
    int gi = i0 + tr * 4 + r;
    if (gi >= N_NODES) continue;
    for (int c = 0; c < 4; ++c) {
      int gj = j0 + tc * 4 + c;
      if (gj < N_NODES) C[(size_t)gi * N_NODES + gj] = 50.0f * acc[r][c];
    }
  }
}

// base = (pad(la) + gumbel)/tau ; fused row-normalize #1 -> u
__global__ void __launch_bounds__(256) k_build(const float* __restrict__ la,
    float* __restrict__ base, float* __restrict__ u, uint32_t k0, uint32_t k1) {
  int i = blockIdx.x;   // 0..1999
  int s = blockIdx.y;   // 0..7
  float* brow = base + ((size_t)s * P + i) * P;
  const int j0 = threadIdx.x * 8;
  float bv[8];
  float lmax = -INFINITY;
  if (j0 < P) {
    uint32_t idxbase = (uint32_t)((s * P + i) * P + j0);
    #pragma unroll
    for (int q = 0; q < 8; ++q) {
      int j = j0 + q;
      float g = gumbel_from_idx(k0, k1, idxbase + (uint32_t)q);
      float lav = (i < N_NODES && j < N_NODES) ? la[(size_t)i * N_NODES + j] : 0.0f;
      bv[q] = (lav + g) / 0.1f;
      lmax = fmaxf(lmax, bv[q]);
    }
    float4* p = (float4*)(brow + j0);
    p[0] = make_float4(bv[0], bv[1], bv[2], bv[3]);
    p[1] = make_float4(bv[4], bv[5], bv[6], bv[7]);
  }
  float M = blockMax256(lmax);
  float ls = 0.f;
  if (j0 < P) {
    #pragma unroll
    for (int q = 0; q < 8; ++q) ls += __expf(bv[q] - M);
  }
  float S = blockSum256(ls);
  if (threadIdx.x == 0) u[s * P + i] = M + __logf(S);
}

// col-pass partial: online LSE over a row chunk, per column (branchless)
__global__ void k_colpartial(const float* __restrict__ base, const float* __restrict__ u,
                             float* __restrict__ pm, float* __restrict__ ps) {
  int j = blockIdx.x * 256 + threadIdx.x;
  int ic = blockIdx.y;
  int s = blockIdx.z;
  float m = -INFINITY, l = 0.f;
  if (j < P) {
    const float* b = base + ((size_t)s * P + ic * ROWS_PER) * P + j;
    const float* uu = u + s * P + ic * ROWS_PER;
    #pragma unroll 4
    for (int r = 0; r < ROWS_PER; ++r) {
      float x = b[(size_t)r * P] - uu[r];
      float nm = fmaxf(m, x);
      l = l * __expf(m - nm) + __expf(x - nm);
      m = nm;
    }
  }
  int o = (s * IC + ic) * 2048 + blockIdx.x * 256 + threadIdx.x;
  pm[o] = m; ps[o] = l;
}

__global__ void k_colcombine(const float* __restrict__ pm, const float* __restrict__ ps,
                             float* __restrict__ v) {
  int j = blockIdx.x * 256 + threadIdx.x;
  int s = blockIdx.y;
  if (j >= P) return;
  float M = -INFINITY;
  for (int c = 0; c < IC; ++c) M = fmaxf(M, pm[(s * IC + c) * 2048 + j]);
  float S = 0.f;
  for (int c = 0; c < IC; ++c) {
    int o = (s * IC + c) * 2048 + j;
    S += ps[o] * __expf(pm[o] - M);
  }
  v[s * P + j] = M + __logf(S);
}

// row pass: u_i = LSE_j(base - v_j)
__global__ void __launch_bounds__(256) k_row(const float* __restrict__ base,
    const float* __restrict__ v, float* __restrict__ u) {
  int i = blockIdx.x, s = blockIdx.y;
  const float* brow = base + ((size_t)s * P + i) * P;
  const float* vv = v + s * P;
  int j0 = threadIdx.x * 8;
  float x[8];
  float lmax = -INFINITY;
  if (j0 < P) {
    float4 b0 = *(const float4*)(brow + j0);
    float4 b1 = *(const float4*)(brow + j0 + 4);
    float4 v0 = *(const float4*)(vv + j0);
    float4 v1 = *(const float4*)(vv + j0 + 4);
    x[0] = b0.x - v0.x; x[1] = b0.y - v0.y; x[2] = b0.z - v0.z; x[3] = b0.w - v0.w;
    x[4] = b1.x - v1.x; x[5] = b1.y - v1.y; x[6] = b1.z - v1.z; x[7] = b1.w - v1.w;
    #pragma unroll
    for (int q = 0; q < 8; ++q) lmax = fmaxf(lmax, x[q]);
  }
  float M = blockMax256(lmax);
  float ls = 0.f;
  if (j0 < P) {
    #pragma unroll
    for (int q = 0; q < 8; ++q) ls += __expf(x[q] - M);
  }
  float S = blockSum256(ls);
  if (threadIdx.x == 0) u[s * P + i] = M + __logf(S);
}

// theta[s,i,j] = exp(base - u - v), only top-left 1000x1000 block
__global__ void k_theta(const float* __restrict__ base, const float* __restrict__ u,
                        const float* __restrict__ v, float* __restrict__ th) {
  int i = blockIdx.x, s = blockIdx.y;
  int j0 = threadIdx.x * 4;
  if (j0 >= N_NODES) return;
  float ui = u[s * P + i];
  const float* brow = base + ((size_t)s * P + i) * P;
  float4 b = *(const float4*)(brow + j0);
  float4 vv = *(const float4*)(v + s * P + j0);
  float4 t;
  t.x = __expf(b.x - ui - vv.x);
  t.y = __expf(b.y - ui - vv.y);
  t.z = __expf(b.z - ui - vv.z);
  t.w = __expf(b.w - ui - vv.w);
  *(float4*)(th + ((size_t)s * N_NODES + i) * N_NODES + j0) = t;
}

__global__ void k_thmean(const float* __restrict__ th, float* __restrict__ thp) {
  int idx = blockIdx.x * 256 + threadIdx.x;
  if (idx < N_NODES * N_NODES) {
    float a = 0.f;
    for (int s = 0; s < NS; ++s) a += th[(size_t)s * N_NODES * N_NODES + idx];
    thp[idx] = a * 0.125f;
  }
}

// gather form: W[s,i,c] = sum over CSR[c] of theta[s,i,part[q]]
__global__ void __launch_bounds__(256) k_wbuild_csr(const float* __restrict__ th,
    const int* __restrict__ start, const int* __restrict__ part, float* __restrict__ Wb) {
  __shared__ float trow[N_NODES];
  int i = blockIdx.x, s = blockIdx.y;
  const float* tr = th + ((size_t)s * N_NODES + i) * N_NODES;
  for (int j = threadIdx.x; j < N_NODES / 4; j += 256)
    ((float4*)trow)[j] = ((const float4*)tr)[j];
  __syncthreads();
  float* wout = Wb + ((size_t)s * N_NODES + i) * N_NODES;
  for (int c = threadIdx.x; c < N_NODES; c += 256) {
    int e0 = start[c], e1 = start[c + 1];
    float a = 0.f;
    for (int q = e0; q < e1; ++q) a += trow[part[q]];
    wout[c] = a;
  }
}

// matched[s] += sum over e1 edges of dot(W[s,e1_0], theta[s,e1_1])
__global__ void __launch_bounds__(256) k_matched(const float* __restrict__ Wb,
    const float* __restrict__ th, const int* __restrict__ es, float* __restrict__ matched) {
  int chunk = blockIdx.x;   // 0..249 (64 edges each)
  int s = blockIdx.y;
  int wave = threadIdx.x >> 6, lane = threadIdx.x & 63;
  float acc = 0.f;
  for (int e = 0; e < 16; ++e) {
    int k = chunk * 64 + wave * 16 + e;
    int a = es[k], b = es[N_EDGES + k];
    const float4* wr = (const float4*)(Wb + ((size_t)s * N_NODES + a) * N_NODES);
    const float4* tr = (const float4*)(th + ((size_t)s * N_NODES + b) * N_NODES);
    #pragma unroll
    for (int q = 0; q < 4; ++q) {
      int f = q * 64 + lane;
      if (f < 250) {
        float4 w4 = wr[f], t4 = tr[f];
        acc += w4.x * t4.x + w4.y * t4.y + w4.z * t4.z + w4.w * t4.w;
      }
    }
  }
  #pragma unroll
  for (int off = 32; off; off >>= 1) acc += __shfl_down(acc, off, 64);
  if (lane == 0) atomicAdd(matched + s, acc);
}

__global__ void k_fin0(const float* __restrict__ matched, float* __restrict__ scal) {
  if (threadIdx.x == 0) {
    float accm = 0.f;
    for (int s = 0; s < NS; ++s) {
      float m = matched[s];
      float rv = m + (-1.0f) * ((16000.0f - m) + (16000.0f - m));
      accm += rv;
    }
    scal[0] = (accm / 8.0f) / 16000.0f;   // r0
  }
}

__global__ void k_fin1(const float* __restrict__ matched, float* __restrict__ scal,
                       float* __restrict__ out) {
  if (threadIdx.x == 0) {
    float accm = 0.f;
    for (int s = 0; s < NS; ++s) {
      float m = matched[s];
      float rv = m + (-1.0f) * ((16000.0f - m) + (16000.0f - m));
      accm += rv;
    }
    float r1 = (accm / 8.0f) / 16000.0f;
    float r0 = scal[0];
    int improved = (r1 > r0) ? 1 : 0;
    scal[1] = r1;
    scal[2] = (float)improved;
    float loss = -r0 - (improved ? r1 : 0.f);
    float cnt = improved ? 2.0f : 1.0f;
    out[(size_t)P * P] = loss / cnt;
  }
}

// write out = pad(la) (2000x2000). cond: only if scal[2]!=0
__global__ void k_out(const float* __restrict__ la, float* __restrict__ out,
                      const float* __restrict__ scal, int cond) {
  if (cond && scal[2] == 0.0f) return;
  int q = blockIdx.x * 256 + threadIdx.x;   // float4 index
  if (q >= P * P / 4) return;
  int row = q / (P / 4);
  int jc = (q % (P / 4)) * 4;
  float4 vv = make_float4(0.f, 0.f, 0.f, 0.f);
  if (row < N_NODES && jc < N_NODES)
    vv = *(const float4*)(la + (size_t)row * N_NODES + jc);
  *(float4*)(out + (size_t)row * P + jc) = vv;
}

// ---------------- launch ----------------
extern "C" void kernel_launch(void* const* d_in, const int* in_sizes, int n_in,
                              void* d_out, int out_size, void* d_ws, size_t ws_size,
                              hipStream_t stream) {
  (void)in_sizes; (void)n_in; (void)out_size; (void)ws_size;
  const float* x_s = (const float*)d_in[0];
  const int*   e_s = (const int*)d_in[1];
  const float* x_t = (const float*)d_in[2];
  const int*   e_t = (const int*)d_in[3];
  const float* W1  = (const float*)d_in[4];
  const float* b1  = (const float*)d_in[5];
  const float* W2  = (const float*)d_in[6];
  const float* b2  = (const float*)d_in[7];
  float* out = (float*)d_out;

  // workspace layout (floats)
  float* ws    = (float*)d_ws;
  float* base  = ws;                       // 32,000,000
  float* theta = base + 32000000;          //  8,000,000
  float* Wb    = theta + 8000000;          //  8,000,000
  float* laA   = Wb + 8000000;             //  1,000,000
  float* laB   = laA + 1000000;            //  1,000,000
  float* thp   = laB + 1000000;            //  1,000,000
  float* h0    = thp + 1000000;            //    256,000
  float* agg   = h0 + 256000;
  float* h1    = agg + 256000;
  float* h2    = h1 + 256000;
  float* hsn   = h2 + 256000;
  float* htn   = hsn + 256000;
  float* uarr  = htn + 256000;             //     16,000
  float* varr  = uarr + 16000;             //     16,000
  float* pm    = varr + 16000;             //    262,144
  float* psum  = pm + 262144;              //    262,144
  float* imp_s = psum + 262144;            //      1,024
  float* imp_t = imp_s + 1024;             //      1,024
  float* matched = imp_t + 1024;           //         16
  float* scal  = matched + 16;             //         16
  // int workspace (CSR structures)
  int* ibase = (int*)(scal + 16);
  int* cnt    = ibase;                     // 1,024
  int* cursor = cnt + 1024;                // 1,024
  int* ids    = cursor + 1024;             // 16,000
  int* startA = ids + 16000;               // 1,008  (graph s by dst)
  int* partA  = startA + 1008;             // 16,000 (-> src)
  int* startB = partA + 16000;             // 1,008  (graph t by dst)
  int* partB  = startB + 1008;             // 16,000 (-> src)
  int* startC = partB + 16000;             // 1,008  (graph t by e0)
  int* partC  = startC + 1008;             // 16,000 (-> e1)

  // ---- CSR builds (3x): key array, partner array, outputs ----
  const int* keys[3]  = { e_s + N_EDGES, e_t + N_EDGES, e_t };
  const int* parts[3] = { e_s,           e_t,           e_t + N_EDGES };
  int* outs_s[3] = { startA, startB, startC };
  int* outs_p[3] = { partA,  partB,  partC };
  for (int r = 0; r < 3; ++r) {
    hipMemsetAsync(cnt, 0, 2048 * sizeof(int), stream);   // cnt + cursor
    k_hist<<<63, 256, 0, stream>>>(keys[r], cnt);
    k_scan<<<1, 1024, 0, stream>>>(cnt, outs_s[r]);
    k_scatter<<<63, 256, 0, stream>>>(keys[r], outs_s[r], cursor, ids);
    k_partfill<<<63, 256, 0, stream>>>(ids, parts[r], outs_p[r]);
  }

  // host-side JAX key schedule: key(42)=[0,42]; foldlike split (partitionable)
  uint32_t k0 = 0u, k1 = 42u;
  uint32_t sub[2][2];
  for (int it = 0; it < 2; ++it) {
    uint32_t nk0, nk1, s0, s1;
    tf2x32(k0, k1, 0u, 0u, &nk0, &nk1);   // next carry key = cipher(0,0)
    tf2x32(k0, k1, 0u, 1u, &s0, &s1);     // subkey        = cipher(0,1)
    sub[it][0] = s0; sub[it][1] = s1;
    k0 = nk0; k1 = nk1;
  }

  for (int it = 0; it < 2; ++it) {
    // importance
    if (it == 0) {
      k_ones<<<4, 256, 0, stream>>>(imp_s, imp_t);
    } else {
      k_rowsum<<<N_NODES, 256, 0, stream>>>(thp, imp_s);
      k_colsum<<<4, 256, 0, stream>>>(thp, imp_t);
    }
    // GNN per graph
    for (int g = 0; g < 2; ++g) {
      const float* x   = g ? x_t : x_s;
      const float* imp = g ? imp_t : imp_s;
      const int* stt   = g ? startB : startA;
      const int* prt   = g ? partB : partA;
      float* hn        = g ? htn : hsn;
      k_scale<<<N_NODES, 256, 0, stream>>>(x, imp, h0);
      k_agg_csr<<<N_NODES, 256, 0, stream>>>(h0, stt, prt, agg);
      k_lin<<<dim3(63, 4), 256, 0, stream>>>(h0, agg, W1, b1, h1, 1);
      k_agg_csr<<<N_NODES, 256, 0, stream>>>(h1, stt, prt, agg);
      k_lin<<<dim3(63, 4), 256, 0, stream>>>(h1, agg, W2, b2, h2, 0);
      k_norm<<<N_NODES, 256, 0, stream>>>(h2, hn);
    }
    // similarity
    float* la = it ? laB : laA;
    k_gemm50<<<dim3(16, 16), 256, 0, stream>>>(hsn, htn, la);
    // gumbel + sinkhorn (10 iterations; row pass 0 fused in build)
    k_build<<<dim3(P, NS), 256, 0, stream>>>(la, base, uarr, sub[it][0], sub[it][1]);
    for (int k = 0; k < 10; ++k) {
      k_colpartial<<<dim3(8, IC, NS), 256, 0, stream>>>(base, uarr, pm, psum);
      k_colcombine<<<dim3(8, NS), 256, 0, stream>>>(pm, psum, varr);
      if (k < 9) k_row<<<dim3(P, NS), 256, 0, stream>>>(base, varr, uarr);
    }
    // theta + reward
    k_theta<<<dim3(N_NODES, NS), 256, 0, stream>>>(base, uarr, varr, theta);
    if (it == 0) k_thmean<<<3907, 256, 0, stream>>>(theta, thp);
    k_wbuild_csr<<<dim3(N_NODES, NS), 256, 0, stream>>>(theta, startC, partC, Wb);
    hipMemsetAsync(matched, 0, NS * 4, stream);
    k_matched<<<dim3(250, NS), 256, 0, stream>>>(Wb, theta, e_s, matched);
    if (it == 0) {
      k_fin0<<<1, 64, 0, stream>>>(matched, scal);
      k_out<<<3907, 256, 0, stream>>>(laA, out, scal, 0);
    } else {
      k_fin1<<<1, 64, 0, stream>>>(matched, scal, out);
      k_out<<<3907, 256, 0, stream>>>(laB, out, scal, 1);
    }
  }
}

// Round 3
// 1907.938 us; speedup vs baseline: 2.0888x; 1.2064x over previous
//
#include <hip/hip_runtime.h>
#include <stdint.h>
#include <math.h>

#define N_NODES 1000
#define DIM 256
#define N_EDGES 16000
#define NS 8            // gumbel samples
#define P 2000          // padded sinkhorn size
#define IC 16           // col-pass row chunks
#define ROWS_PER (P / IC)

// ---------------- Threefry-2x32 (exact JAX) ----------------
__host__ __device__ inline void tf2x32(uint32_t k0, uint32_t k1,
                                       uint32_t x0, uint32_t x1,
                                       uint32_t* o0, uint32_t* o1) {
  const uint32_t ks2 = k0 ^ k1 ^ 0x1BD11BDAu;
  uint32_t a = x0 + k0, b = x1 + k1;
#define RL(v, d) (((v) << (d)) | ((v) >> (32 - (d))))
#define RND(r) { a += b; b = RL(b, r); b ^= a; }
  RND(13) RND(15) RND(26) RND(6)
  a += k1;  b += ks2 + 1u;
  RND(17) RND(29) RND(16) RND(24)
  a += ks2; b += k0 + 2u;
  RND(13) RND(15) RND(26) RND(6)
  a += k0;  b += k1 + 3u;
  RND(17) RND(29) RND(16) RND(24)
  a += k1;  b += ks2 + 4u;
  RND(13) RND(15) RND(26) RND(6)
  a += ks2; b += k0 + 5u;
#undef RND
#undef RL
  *o0 = a; *o1 = b;
}

// partitionable 32-bit bits: xor-fold of cipher(hi=0, lo=idx)
__device__ inline float gumbel_from_idx(uint32_t k0, uint32_t k1, uint32_t idx) {
  uint32_t b0, b1;
  tf2x32(k0, k1, 0u, idx, &b0, &b1);
  uint32_t bits = b0 ^ b1;
  float u = __uint_as_float((bits >> 9) | 0x3f800000u) - 1.0f;
  return -logf(-logf(u + 1e-20f) + 1e-20f);
}

// ---------------- block reductions (blockDim==256) ----------------
__device__ inline float blockSum256(float v) {
  __shared__ float sm[4];
  #pragma unroll
  for (int off = 32; off; off >>= 1) v += __shfl_down(v, off, 64);
  if ((threadIdx.x & 63) == 0) sm[threadIdx.x >> 6] = v;
  __syncthreads();
  float r = (sm[0] + sm[1]) + (sm[2] + sm[3]);
  __syncthreads();
  return r;
}
__device__ inline float blockMax256(float v) {
  __shared__ float sm[4];
  #pragma unroll
  for (int off = 32; off; off >>= 1) v = fmaxf(v, __shfl_down(v, off, 64));
  if ((threadIdx.x & 63) == 0) sm[threadIdx.x >> 6] = v;
  __syncthreads();
  float r = fmaxf(fmaxf(sm[0], sm[1]), fmaxf(sm[2], sm[3]));
  __syncthreads();
  return r;
}

// ---------------- CSR build (edge lists are static; built once per launch) --
__global__ void k_hist(const int* __restrict__ key, int* __restrict__ cnt) {
  int k = blockIdx.x * 256 + threadIdx.x;
  if (k < N_EDGES) atomicAdd(&cnt[key[k]], 1);
}
__global__ void k_scan(const int* __restrict__ cnt, int* __restrict__ start) {
  __shared__ int sm[1024];
  int t = threadIdx.x;
  sm[t] = (t < N_NODES) ? cnt[t] : 0;
  __syncthreads();
  for (int off = 1; off < 1024; off <<= 1) {
    int v = (t >= off) ? sm[t - off] : 0;
    __syncthreads();
    sm[t] += v;
    __syncthreads();
  }
  if (t < N_NODES) start[t + 1] = sm[t];
  if (t == 0) start[0] = 0;
}
__global__ void k_scatter(const int* __restrict__ key, const int* __restrict__ start,
                          int* __restrict__ cursor, int* __restrict__ ids) {
  int k = blockIdx.x * 256 + threadIdx.x;
  if (k < N_EDGES) {
    int c = key[k];
    int slot = start[c] + atomicAdd(&cursor[c], 1);
    ids[slot] = k;
  }
}
__global__ void k_partfill(const int* __restrict__ ids, const int* __restrict__ pv,
                           int* __restrict__ part) {
  int s = blockIdx.x * 256 + threadIdx.x;
  if (s < N_EDGES) part[s] = pv[ids[s]];
}
// pack e_t edges: (c<<10)|d  with c=e_t[0][m], d=e_t[1][m] (both < 1024)
__global__ void k_pack(const int* __restrict__ et, int* __restrict__ epack) {
  int m = blockIdx.x * 256 + threadIdx.x;
  if (m < N_EDGES) epack[m] = (et[m] << 10) | et[N_EDGES + m];
}

// ---------------- small kernels ----------------
__global__ void k_ones(float* imp_s, float* imp_t) {
  int t = blockIdx.x * 256 + threadIdx.x;
  if (t < N_NODES) { imp_s[t] = 1.0f; imp_t[t] = 1.0f; }
}

__global__ void k_rowsum(const float* __restrict__ thp, float* __restrict__ imp) {
  int i = blockIdx.x;
  float a = 0.f;
  for (int j = threadIdx.x; j < N_NODES; j += 256) a += thp[(size_t)i * N_NODES + j];
  float s = blockSum256(a);
  if (threadIdx.x == 0) imp[i] = s;
}

__global__ void k_colsum(const float* __restrict__ thp, float* __restrict__ imp) {
  int j = blockIdx.x * 256 + threadIdx.x;
  if (j >= N_NODES) return;
  float a = 0.f;
  for (int i = 0; i < N_NODES; ++i) a += thp[(size_t)i * N_NODES + j];
  imp[j] = a;
}

__global__ void k_scale(const float* __restrict__ x, const float* __restrict__ imp,
                        float* __restrict__ h) {
  int i = blockIdx.x, d = threadIdx.x;
  h[i * DIM + d] = x[i * DIM + d] * imp[i];
}

// gather form of segment_sum: agg[i,d] = sum over CSR[dst=i] of h[src,d]
__global__ void k_agg_csr(const float* __restrict__ h, const int* __restrict__ start,
                          const int* __restrict__ part, float* __restrict__ agg) {
  int i = blockIdx.x, d = threadIdx.x;
  int e0 = start[i], e1 = start[i + 1];
  float a = 0.f;
  for (int q = e0; q < e1; ++q) a += h[(size_t)part[q] * DIM + d];
  agg[i * DIM + d] = a;
}

// out = act((h+agg) @ Wm + bias); M=1000,K=N=256. tile 16x64
__global__ void __launch_bounds__(256) k_lin(const float* __restrict__ h,
    const float* __restrict__ agg, const float* __restrict__ Wm,
    const float* __restrict__ bias, float* __restrict__ out, int relu) {
  __shared__ float As[16][64];
  __shared__ float Ws[64][64];
  int tx = threadIdx.x & 63;
  int ty = threadIdx.x >> 6;
  int row0 = blockIdx.x * 16;
  int col0 = blockIdx.y * 64;
  float acc[4] = {0.f, 0.f, 0.f, 0.f};
  for (int kc = 0; kc < DIM; kc += 64) {
    for (int t = threadIdx.x; t < 16 * 64; t += 256) {
      int r = t >> 6, c = t & 63;
      int gr = row0 + r;
      As[r][c] = (gr < N_NODES) ? (h[gr * DIM + kc + c] + agg[gr * DIM + kc + c]) : 0.f;
    }
    for (int t = threadIdx.x; t < 64 * 64; t += 256) {
      int r = t >> 6, c = t & 63;
      Ws[r][c] = Wm[(kc + r) * DIM + col0 + c];
    }
    __syncthreads();
    #pragma unroll 8
    for (int kk = 0; kk < 64; ++kk) {
      float w = Ws[kk][tx];
      acc[0] += As[ty][kk] * w;
      acc[1] += As[ty + 4][kk] * w;
      acc[2] += As[ty + 8][kk] * w;
      acc[3] += As[ty + 12][kk] * w;
    }
    __syncthreads();
  }
  int col = col0 + tx;
  float bv = bias[col];
  #pragma unroll
  for (int r = 0; r < 4; ++r) {
    int gr = row0 + ty + r * 4;
    if (gr < N_NODES) {
      float vv = acc[r] + bv;
      if (relu) vv = fmaxf(vv, 0.f);
      out[gr * DIM + col] = vv;
    }
  }
}

__global__ void k_norm(const float* __restrict__ h, float* __restrict__ out) {
  int i = blockIdx.x;
  float x = h[i * DIM + threadIdx.x];
  float ss = blockSum256(x * x);
  float nrm = sqrtf(ss);
  out[i * DIM + threadIdx.x] = x / nrm;
}

// C[i][j] = 50 * dot(A[i,:], B[j,:]) ; A,B 1000x256, C 1000x1000
__global__ void __launch_bounds__(256) k_gemm50(const float* __restrict__ A,
    const float* __restrict__ B, float* __restrict__ C) {
  __shared__ float As[64][33];
  __shared__ float Bs[64][33];
  int tr = threadIdx.x >> 4;
  int tc = threadIdx.x & 15;
  int i0 = blockIdx.x * 64, j0 = blockIdx.y * 64;
  float acc[4][4] = {};
  for (int kc = 0; kc < DIM; kc += 32) {
    for (int t = threadIdx.x; t < 64 * 32; t += 256) {
      int r = t >> 5, c = t & 31;
      int gi = i0 + r; As[r][c] = (gi < N_NODES) ? A[gi * DIM + kc + c] : 0.f;
      int gj = j0 + r; Bs[r][c] = (gj < N_NODES) ? B[gj * DIM + kc + c] : 0.f;
    }
    __syncthreads();
    for (int kk = 0; kk < 32; ++kk) {
      float a[4], b[4];
      #pragma unroll
      for (int q = 0; q < 4; ++q) a[q] = As[tr * 4 + q][kk];
      #pragma unroll
      for (int q = 0; q < 4; ++q) b[q] = Bs[tc * 4 + q][kk];
      #pragma unroll
      for (int r = 0; r < 4; ++r)
        #pragma unroll
        for (int c = 0; c < 4; ++c) acc[r][c] += a[r] * b[c];
    }
    __syncthreads();
  }
  for (int r = 0; r < 4; ++r) {
    int gi = i0 + tr * 4 + r;
    if (gi >= N_NODES) continue;
    for (int c = 0; c < 4; ++c) {
      int gj = j0 + tc * 4 + c;
      if (gj < N_NODES) C[(size_t)gi * N_NODES + gj] = 50.0f * acc[r][c];
    }
  }
}

// base = (pad(la) + gumbel)/tau ; fused row-normalize #1 -> u
__global__ void __launch_bounds__(256) k_build(const float* __restrict__ la,
    float* __restrict__ base, float* __restrict__ u, uint32_t k0, uint32_t k1) {
  int i = blockIdx.x;   // 0..1999
  int s = blockIdx.y;   // 0..7
  float* brow = base + ((size_t)s * P + i) * P;
  const int j0 = threadIdx.x * 8;
  float bv[8];
  float lmax = -INFINITY;
  if (j0 < P) {
    uint32_t idxbase = (uint32_t)((s * P + i) * P + j0);
    #pragma unroll
    for (int q = 0; q < 8; ++q) {
      int j = j0 + q;
      float g = gumbel_from_idx(k0, k1, idxbase + (uint32_t)q);
      float lav = (i < N_NODES && j < N_NODES) ? la[(size_t)i * N_NODES + j] : 0.0f;
      bv[q] = (lav + g) / 0.1f;
      lmax = fmaxf(lmax, bv[q]);
    }
    float4* p = (float4*)(brow + j0);
    p[0] = make_float4(bv[0], bv[1], bv[2], bv[3]);
    p[1] = make_float4(bv[4], bv[5], bv[6], bv[7]);
  }
  float M = blockMax256(lmax);
  float ls = 0.f;
  if (j0 < P) {
    #pragma unroll
    for (int q = 0; q < 8; ++q) ls += __expf(bv[q] - M);
  }
  float S = blockSum256(ls);
  if (threadIdx.x == 0) u[s * P + i] = M + __logf(S);
}

// col-pass partial: online LSE over a row chunk, per column (branchless)
__global__ void k_colpartial(const float* __restrict__ base, const float* __restrict__ u,
                             float* __restrict__ pm, float* __restrict__ ps) {
  int j = blockIdx.x * 256 + threadIdx.x;
  int ic = blockIdx.y;
  int s = blockIdx.z;
  float m = -INFINITY, l = 0.f;
  if (j < P) {
    const float* b = base + ((size_t)s * P + ic * ROWS_PER) * P + j;
    const float* uu = u + s * P + ic * ROWS_PER;
    #pragma unroll 4
    for (int r = 0; r < ROWS_PER; ++r) {
      float x = b[(size_t)r * P] - uu[r];
      float nm = fmaxf(m, x);
      l = l * __expf(m - nm) + __expf(x - nm);
      m = nm;
    }
  }
  int o = (s * IC + ic) * 2048 + blockIdx.x * 256 + threadIdx.x;
  pm[o] = m; ps[o] = l;
}

__global__ void k_colcombine(const float* __restrict__ pm, const float* __restrict__ ps,
                             float* __restrict__ v) {
  int j = blockIdx.x * 256 + threadIdx.x;
  int s = blockIdx.y;
  if (j >= P) return;
  float M = -INFINITY;
  for (int c = 0; c < IC; ++c) M = fmaxf(M, pm[(s * IC + c) * 2048 + j]);
  float S = 0.f;
  for (int c = 0; c < IC; ++c) {
    int o = (s * IC + c) * 2048 + j;
    S += ps[o] * __expf(pm[o] - M);
  }
  v[s * P + j] = M + __logf(S);
}

// row pass: u_i = LSE_j(base - v_j)
__global__ void __launch_bounds__(256) k_row(const float* __restrict__ base,
    const float* __restrict__ v, float* __restrict__ u) {
  int i = blockIdx.x, s = blockIdx.y;
  const float* brow = base + ((size_t)s * P + i) * P;
  const float* vv = v + s * P;
  int j0 = threadIdx.x * 8;
  float x[8];
  float lmax = -INFINITY;
  if (j0 < P) {
    float4 b0 = *(const float4*)(brow + j0);
    float4 b1 = *(const float4*)(brow + j0 + 4);
    float4 v0 = *(const float4*)(vv + j0);
    float4 v1 = *(const float4*)(vv + j0 + 4);
    x[0] = b0.x - v0.x; x[1] = b0.y - v0.y; x[2] = b0.z - v0.z; x[3] = b0.w - v0.w;
    x[4] = b1.x - v1.x; x[5] = b1.y - v1.y; x[6] = b1.z - v1.z; x[7] = b1.w - v1.w;
    #pragma unroll
    for (int q = 0; q < 8; ++q) lmax = fmaxf(lmax, x[q]);
  }
  float M = blockMax256(lmax);
  float ls = 0.f;
  if (j0 < P) {
    #pragma unroll
    for (int q = 0; q < 8; ++q) ls += __expf(x[q] - M);
  }
  float S = blockSum256(ls);
  if (threadIdx.x == 0) u[s * P + i] = M + __logf(S);
}

// theta[s,i,j] = exp(base - u - v), only top-left 1000x1000 block
__global__ void k_theta(const float* __restrict__ base, const float* __restrict__ u,
                        const float* __restrict__ v, float* __restrict__ th) {
  int i = blockIdx.x, s = blockIdx.y;
  int j0 = threadIdx.x * 4;
  if (j0 >= N_NODES) return;
  float ui = u[s * P + i];
  const float* brow = base + ((size_t)s * P + i) * P;
  float4 b = *(const float4*)(brow + j0);
  float4 vv = *(const float4*)(v + s * P + j0);
  float4 t;
  t.x = __expf(b.x - ui - vv.x);
  t.y = __expf(b.y - ui - vv.y);
  t.z = __expf(b.z - ui - vv.z);
  t.w = __expf(b.w - ui - vv.w);
  *(float4*)(th + ((size_t)s * N_NODES + i) * N_NODES + j0) = t;
}

__global__ void k_thmean(const float* __restrict__ th, float* __restrict__ thp) {
  int idx = blockIdx.x * 256 + threadIdx.x;
  if (idx < N_NODES * N_NODES) {
    float a = 0.f;
    for (int s = 0; s < NS; ++s) a += th[(size_t)s * N_NODES * N_NODES + idx];
    thp[idx] = a * 0.125f;
  }
}

// fused reward: matched[s] = sum_b sum_{e2=(c,d)} Y[s,b,d] * th[s,b,c]
// with Y[s,b,:] = sum_{e1 edges (a->b)} th[s,a,:]   (CSR: startA/partA by e1_1)
__global__ void __launch_bounds__(256) k_reward(const float* __restrict__ th,
    const int* __restrict__ start, const int* __restrict__ part,
    const int* __restrict__ epack, float* __restrict__ matched) {
  __shared__ float yrow[N_NODES];
  __shared__ float xrow[N_NODES];
  int b = blockIdx.x, s = blockIdx.y;
  const float* xr = th + ((size_t)s * N_NODES + b) * N_NODES;
  // xrow load + yrow register-accumulate (thread t owns float4 index t, t<250)
  int t = threadIdx.x;
  float4 y4 = make_float4(0.f, 0.f, 0.f, 0.f);
  if (t < 250) {
    ((float4*)xrow)[t] = ((const float4*)xr)[t];
    int e0 = start[b], e1 = start[b + 1];
    for (int q = e0; q < e1; ++q) {
      const float4* rr = (const float4*)(th + ((size_t)s * N_NODES + part[q]) * N_NODES);
      float4 vv = rr[t];
      y4.x += vv.x; y4.y += vv.y; y4.z += vv.z; y4.w += vv.w;
    }
    ((float4*)yrow)[t] = y4;
  }
  __syncthreads();
  float acc = 0.f;
  for (int m = t; m < N_EDGES; m += 256) {
    int pk = epack[m];
    acc += yrow[pk & 1023] * xrow[pk >> 10];
  }
  float ssum = blockSum256(acc);
  if (t == 0) atomicAdd(matched + s, ssum);
}

__global__ void k_fin0(const float* __restrict__ matched, float* __restrict__ scal) {
  if (threadIdx.x == 0) {
    float accm = 0.f;
    for (int s = 0; s < NS; ++s) {
      float m = matched[s];
      float rv = m + (-1.0f) * ((16000.0f - m) + (16000.0f - m));
      accm += rv;
    }
    scal[0] = (accm / 8.0f) / 16000.0f;   // r0
  }
}

__global__ void k_fin1(const float* __restrict__ matched, float* __restrict__ scal,
                       float* __restrict__ out) {
  if (threadIdx.x == 0) {
    float accm = 0.f;
    for (int s = 0; s < NS; ++s) {
      float m = matched[s];
      float rv = m + (-1.0f) * ((16000.0f - m) + (16000.0f - m));
      accm += rv;
    }
    float r1 = (accm / 8.0f) / 16000.0f;
    float r0 = scal[0];
    int improved = (r1 > r0) ? 1 : 0;
    scal[1] = r1;
    scal[2] = (float)improved;
    float loss = -r0 - (improved ? r1 : 0.f);
    float cnt = improved ? 2.0f : 1.0f;
    out[(size_t)P * P] = loss / cnt;
  }
}

// write out = pad(la) (2000x2000). cond: only if scal[2]!=0
__global__ void k_out(const float* __restrict__ la, float* __restrict__ out,
                      const float* __restrict__ scal, int cond) {
  if (cond && scal[2] == 0.0f) return;
  int q = blockIdx.x * 256 + threadIdx.x;   // float4 index
  if (q >= P * P / 4) return;
  int row = q / (P / 4);
  int jc = (q % (P / 4)) * 4;
  float4 vv = make_float4(0.f, 0.f, 0.f, 0.f);
  if (row < N_NODES && jc < N_NODES)
    vv = *(const float4*)(la + (size_t)row * N_NODES + jc);
  *(float4*)(out + (size_t)row * P + jc) = vv;
}

// ---------------- launch ----------------
extern "C" void kernel_launch(void* const* d_in, const int* in_sizes, int n_in,
                              void* d_out, int out_size, void* d_ws, size_t ws_size,
                              hipStream_t stream) {
  (void)in_sizes; (void)n_in; (void)out_size; (void)ws_size;
  const float* x_s = (const float*)d_in[0];
  const int*   e_s = (const int*)d_in[1];
  const float* x_t = (const float*)d_in[2];
  const int*   e_t = (const int*)d_in[3];
  const float* W1  = (const float*)d_in[4];
  const float* b1  = (const float*)d_in[5];
  const float* W2  = (const float*)d_in[6];
  const float* b2  = (const float*)d_in[7];
  float* out = (float*)d_out;

  // workspace layout (floats)
  float* ws    = (float*)d_ws;
  float* base  = ws;                       // 32,000,000
  float* theta = base + 32000000;          //  8,000,000
  float* laA   = theta + 8000000;          //  1,000,000
  float* laB   = laA + 1000000;            //  1,000,000
  float* thp   = laB + 1000000;            //  1,000,000
  float* h0    = thp + 1000000;            //    256,000
  float* agg   = h0 + 256000;
  float* h1    = agg + 256000;
  float* h2    = h1 + 256000;
  float* hsn   = h2 + 256000;
  float* htn   = hsn + 256000;
  float* uarr  = htn + 256000;             //     16,000
  float* varr  = uarr + 16000;             //     16,000
  float* pm    = varr + 16000;             //    262,144
  float* psum  = pm + 262144;              //    262,144
  float* imp_s = psum + 262144;            //      1,024
  float* imp_t = imp_s + 1024;             //      1,024
  float* matched = imp_t + 1024;           //         16
  float* scal  = matched + 16;             //         16
  // int workspace (CSR structures)
  int* ibase = (int*)(scal + 16);
  int* cnt    = ibase;                     // 1,024
  int* cursor = cnt + 1024;                // 1,024
  int* ids    = cursor + 1024;             // 16,000
  int* startA = ids + 16000;               // 1,008  (graph s by e1_1/dst -> e1_0/src)
  int* partA  = startA + 1008;             // 16,000
  int* startB = partA + 16000;             // 1,008  (graph t by dst -> src)
  int* partB  = startB + 1008;             // 16,000
  int* epack  = partB + 16000;             // 16,000 (packed e_t: (c<<10)|d)

  // ---- CSR builds (2x) + edge pack ----
  const int* keys[2]  = { e_s + N_EDGES, e_t + N_EDGES };
  const int* parts[2] = { e_s,           e_t           };
  int* outs_s[2] = { startA, startB };
  int* outs_p[2] = { partA,  partB  };
  for (int r = 0; r < 2; ++r) {
    hipMemsetAsync(cnt, 0, 2048 * sizeof(int), stream);   // cnt + cursor
    k_hist<<<63, 256, 0, stream>>>(keys[r], cnt);
    k_scan<<<1, 1024, 0, stream>>>(cnt, outs_s[r]);
    k_scatter<<<63, 256, 0, stream>>>(keys[r], outs_s[r], cursor, ids);
    k_partfill<<<63, 256, 0, stream>>>(ids, parts[r], outs_p[r]);
  }
  k_pack<<<63, 256, 0, stream>>>(e_t, epack);

  // host-side JAX key schedule: key(42)=[0,42]; foldlike split (partitionable)
  uint32_t k0 = 0u, k1 = 42u;
  uint32_t sub[2][2];
  for (int it = 0; it < 2; ++it) {
    uint32_t nk0, nk1, s0, s1;
    tf2x32(k0, k1, 0u, 0u, &nk0, &nk1);   // next carry key = cipher(0,0)
    tf2x32(k0, k1, 0u, 1u, &s0, &s1);     // subkey        = cipher(0,1)
    sub[it][0] = s0; sub[it][1] = s1;
    k0 = nk0; k1 = nk1;
  }

  for (int it = 0; it < 2; ++it) {
    // importance
    if (it == 0) {
      k_ones<<<4, 256, 0, stream>>>(imp_s, imp_t);
    } else {
      k_rowsum<<<N_NODES, 256, 0, stream>>>(thp, imp_s);
      k_colsum<<<4, 256, 0, stream>>>(thp, imp_t);
    }
    // GNN per graph
    for (int g = 0; g < 2; ++g) {
      const float* x   = g ? x_t : x_s;
      const float* imp = g ? imp_t : imp_s;
      const int* stt   = g ? startB : startA;
      const int* prt   = g ? partB : partA;
      float* hn        = g ? htn : hsn;
      k_scale<<<N_NODES, 256, 0, stream>>>(x, imp, h0);
      k_agg_csr<<<N_NODES, 256, 0, stream>>>(h0, stt, prt, agg);
      k_lin<<<dim3(63, 4), 256, 0, stream>>>(h0, agg, W1, b1, h1, 1);
      k_agg_csr<<<N_NODES, 256, 0, stream>>>(h1, stt, prt, agg);
      k_lin<<<dim3(63, 4), 256, 0, stream>>>(h1, agg, W2, b2, h2, 0);
      k_norm<<<N_NODES, 256, 0, stream>>>(h2, hn);
    }
    // similarity
    float* la = it ? laB : laA;
    k_gemm50<<<dim3(16, 16), 256, 0, stream>>>(hsn, htn, la);
    // gumbel + sinkhorn (10 iterations; row pass 0 fused in build)
    k_build<<<dim3(P, NS), 256, 0, stream>>>(la, base, uarr, sub[it][0], sub[it][1]);
    for (int k = 0; k < 10; ++k) {
      k_colpartial<<<dim3(8, IC, NS), 256, 0, stream>>>(base, uarr, pm, psum);
      k_colcombine<<<dim3(8, NS), 256, 0, stream>>>(pm, psum, varr);
      if (k < 9) k_row<<<dim3(P, NS), 256, 0, stream>>>(base, varr, uarr);
    }
    // theta + reward
    k_theta<<<dim3(N_NODES, NS), 256, 0, stream>>>(base, uarr, varr, theta);
    if (it == 0) k_thmean<<<3907, 256, 0, stream>>>(theta, thp);
    hipMemsetAsync(matched, 0, NS * 4, stream);
    k_reward<<<dim3(N_NODES, NS), 256, 0, stream>>>(theta, startA, partA, epack, matched);
    if (it == 0) {
      k_fin0<<<1, 64, 0, stream>>>(matched, scal);
      k_out<<<3907, 256, 0, stream>>>(laA, out, scal, 0);
    } else {
      k_fin1<<<1, 64, 0, stream>>>(matched, scal, out);
      k_out<<<3907, 256, 0, stream>>>(laB, out, scal, 1);
    }
  }
}